// Round 6
// baseline (433.185 us; speedup 1.0000x reference)
//
#include <hip/hip_runtime.h>

#define NEG 0.2f
#define CHUNK 2048   // edges per CSR-build block (256 thr x 8)

using bf16x8 = __attribute__((ext_vector_type(8))) short;
using f32x4  = __attribute__((ext_vector_type(4))) float;

__device__ __forceinline__ short f2bf(float f) {   // RNE round to bf16 bits
    union { float f; unsigned u; } v; v.f = f;
    unsigned r = v.u + 0x7FFFu + ((v.u >> 16) & 1u);
    return (short)(r >> 16);
}
__device__ __forceinline__ float bflo(unsigned v) {
    union { unsigned u; float f; } x; x.u = v << 16; return x.f;
}
__device__ __forceinline__ float bfhi(unsigned v) {
    union { unsigned u; float f; } x; x.u = v & 0xffff0000u; return x.f;
}

// ---------------------------------------------------------------------------
// k_pd: blocks [0,16) transpose W -> bf16 Wbf[c*128+k]; blocks [16,..) count
// dst degrees, dst-range partitioned (range r = b&7 keeps atomic lines on one
// XCD under round-robin blockIdx->XCD dispatch).
// ---------------------------------------------------------------------------
__global__ __launch_bounds__(256) void k_pd(const float* __restrict__ W,
                                            unsigned short* __restrict__ Wbf,
                                            const int* __restrict__ dst,
                                            int* __restrict__ deg,
                                            int E, int N8) {
    if (blockIdx.x < 16) {
        int idx = (blockIdx.x * 256 + threadIdx.x) * 4;
        #pragma unroll
        for (int q = 0; q < 4; ++q) {
            int i = idx + q;            // i = k*128 + c
            int k = i >> 7, c = i & 127;
            Wbf[c * 128 + k] = (unsigned short)f2bf(W[i]);
        }
        return;
    }
    int b = blockIdx.x - 16;
    int r = b & 7;
    int c = b >> 3;
    int lo = r * N8, hi = lo + N8;
    int base = c * CHUNK + threadIdx.x;
    #pragma unroll
    for (int q = 0; q < 8; ++q) {
        int e = base + q * 256;
        if (e < E) {
            int d = dst[e];
            if (d >= lo && d < hi) atomicAdd(&deg[d], 1);
        }
    }
}

// ---------------------------------------------------------------------------
// k_gemm_scan: blocks [0,GB) compute h(bf16) = bf16(feats) @ Wbf via
// mfma_f32_16x16x32_bf16 (B-fragments straight from L1/L2-resident Wbf).
// Block GB is a single-block full exclusive scan of deg -> rowptr/cursor
// (hidden under the gemm; replaces 3 dispatches).
// ---------------------------------------------------------------------------
__global__ __launch_bounds__(256) void k_gemm_scan(const float* __restrict__ feats,
                                                   const unsigned short* __restrict__ Wbf,
                                                   unsigned short* __restrict__ h,
                                                   const int* __restrict__ deg,
                                                   int* __restrict__ rowptr,
                                                   int* __restrict__ cursor,
                                                   int N, int E, int GB) {
    if ((int)blockIdx.x == GB) {
        // ---- single-block scan: 256 threads x PER contiguous elements ----
        __shared__ int sd[256];
        const int t = threadIdx.x;
        const int PER = ((N + 1023) >> 10) << 2;   // per-thread count, mult of 4
        const int start = t * PER;
        int tsum = 0;
        for (int i = 0; i < PER; i += 4) {
            int idx = start + i;
            if (idx + 3 < N) {
                int4 v = *(const int4*)(deg + idx);
                tsum += v.x + v.y + v.z + v.w;
            } else {
                for (int q = idx; q < N && q < idx + 4; ++q) tsum += deg[q];
            }
        }
        sd[t] = tsum;
        __syncthreads();
        for (int off = 1; off < 256; off <<= 1) {
            int x = (t >= off) ? sd[t - off] : 0;
            __syncthreads();
            sd[t] += x;
            __syncthreads();
        }
        int run = sd[t] - tsum;   // exclusive prefix for this thread's range
        for (int i = 0; i < PER; i += 4) {
            int idx = start + i;
            if (idx + 3 < N) {
                int4 v = *(const int4*)(deg + idx);
                int r0 = run, r1 = r0 + v.x, r2 = r1 + v.y, r3 = r2 + v.z;
                *(int4*)(rowptr + idx) = make_int4(r0, r1, r2, r3);
                *(int4*)(cursor + idx) = make_int4(r0, r1, r2, r3);
                run = r3 + v.w;
            } else {
                for (int q = idx; q < N && q < idx + 4; ++q) {
                    rowptr[q] = run; cursor[q] = run; run += deg[q];
                }
            }
        }
        if (t == 255) rowptr[N] = E;
        return;
    }

    // ---- gemm ----
    const int t    = threadIdx.x;
    const int n0   = blockIdx.x * 64;
    const int w    = t >> 6;
    const int lane = t & 63;
    const int m    = lane & 15;
    const int quad = lane >> 4;
    const int kq   = quad * 8;

    const int row_a = n0 + w * 16 + m;
    const bool va = (row_a < N);

    f32x4 acc[8];
    #pragma unroll
    for (int ti = 0; ti < 8; ++ti) acc[ti] = (f32x4){0.f, 0.f, 0.f, 0.f};

    #pragma unroll
    for (int kc = 0; kc < 4; ++kc) {
        const float* ap = feats + (size_t)row_a * 128 + kc * 32 + kq;
        float4 a0 = va ? ((const float4*)ap)[0] : make_float4(0.f,0.f,0.f,0.f);
        float4 a1 = va ? ((const float4*)ap)[1] : make_float4(0.f,0.f,0.f,0.f);
        bf16x8 af;
        af[0] = f2bf(a0.x); af[1] = f2bf(a0.y); af[2] = f2bf(a0.z); af[3] = f2bf(a0.w);
        af[4] = f2bf(a1.x); af[5] = f2bf(a1.y); af[6] = f2bf(a1.z); af[7] = f2bf(a1.w);
        #pragma unroll
        for (int ti = 0; ti < 8; ++ti) {
            bf16x8 bf = *(const bf16x8*)&Wbf[(size_t)(ti * 16 + m) * 128 + kc * 32 + kq];
            acc[ti] = __builtin_amdgcn_mfma_f32_16x16x32_bf16(af, bf, acc[ti], 0, 0, 0);
        }
    }

    // C layout: col = ti*16 + m, row = row_d + r
    const int row_d = n0 + w * 16 + quad * 4;
    #pragma unroll
    for (int ti = 0; ti < 8; ++ti) {
        int col = ti * 16 + m;
        #pragma unroll
        for (int r = 0; r < 4; ++r) {
            int row = row_d + r;
            if (row < N) h[(size_t)row * 128 + col] = (unsigned short)f2bf(acc[ti][r]);
        }
    }
}

// ---------------------------------------------------------------------------
// k_ef: blocks [0,BE) compute el/er per (node,head) from bf16 h; remaining
// blocks fill CSR (dst-range partitioned, same XCD-locality trick — constant
// blockIdx offset preserves the r -> XCD mapping).
// ---------------------------------------------------------------------------
__global__ __launch_bounds__(256) void k_ef(const unsigned short* __restrict__ h,
                                            const float* __restrict__ attn_l,
                                            const float* __restrict__ attn_r,
                                            float* __restrict__ el,
                                            float* __restrict__ er,
                                            const int* __restrict__ src,
                                            const int* __restrict__ dst,
                                            int* __restrict__ cursor,
                                            int* __restrict__ csr_src,
                                            int N, int E, int N8, int BE) {
    if ((int)blockIdx.x < BE) {
        int t = blockIdx.x * 256 + threadIdx.x;   // t = n*8 + head
        int n = t >> 3, hd = t & 7;
        if (n >= N) return;
        const uint4* hp = (const uint4*)(h + (size_t)n * 128 + hd * 16);
        uint4 u0 = hp[0], u1 = hp[1];
        const float4* al = (const float4*)(attn_l + hd * 16);
        const float4* ar = (const float4*)(attn_r + hd * 16);
        float hv[16];
        hv[0]=bflo(u0.x); hv[1]=bfhi(u0.x); hv[2]=bflo(u0.y); hv[3]=bfhi(u0.y);
        hv[4]=bflo(u0.z); hv[5]=bfhi(u0.z); hv[6]=bflo(u0.w); hv[7]=bfhi(u0.w);
        hv[8]=bflo(u1.x); hv[9]=bfhi(u1.x); hv[10]=bflo(u1.y); hv[11]=bfhi(u1.y);
        hv[12]=bflo(u1.z); hv[13]=bfhi(u1.z); hv[14]=bflo(u1.w); hv[15]=bfhi(u1.w);
        float sl = 0.f, sr = 0.f;
        #pragma unroll
        for (int q = 0; q < 4; ++q) {
            float4 a = al[q], b = ar[q];
            sl += hv[4*q]*a.x + hv[4*q+1]*a.y + hv[4*q+2]*a.z + hv[4*q+3]*a.w;
            sr += hv[4*q]*b.x + hv[4*q+1]*b.y + hv[4*q+2]*b.z + hv[4*q+3]*b.w;
        }
        el[t] = sl;
        er[t] = sr;
        return;
    }
    int b = blockIdx.x - BE;
    int r = b & 7;
    int c = b >> 3;
    int lo = r * N8, hi = lo + N8;
    int base = c * CHUNK + threadIdx.x;
    #pragma unroll
    for (int q = 0; q < 8; ++q) {
        int e = base + q * 256;
        if (e < E) {
            int d = dst[e];
            if (d >= lo && d < hi) {
                int p = atomicAdd(&cursor[d], 1);
                csr_src[p] = src[e];
            }
        }
    }
}

// ---------------------------------------------------------------------------
// k_agg: gather aggregation, one wave per node; quarter q handles edges
// begin+q, +4, ... with 2-edge unroll (8 edges in flight per wave).
// ---------------------------------------------------------------------------
__global__ __launch_bounds__(256) void k_agg(const int* __restrict__ rowptr,
                                             const int* __restrict__ csr_src,
                                             const float* __restrict__ el,
                                             const float* __restrict__ er,
                                             const unsigned short* __restrict__ h,
                                             const float* __restrict__ bias,
                                             float* __restrict__ out, int N) {
    int t = threadIdx.x;
    int n = blockIdx.x * 4 + (t >> 6);
    if (n >= N) return;
    int lane = t & 63;
    int q    = lane >> 4;      // edge slot 0..3
    int c16  = lane & 15;      // col group: cols 8*c16..8*c16+7
    int hd   = c16 >> 1;
    int begin = rowptr[n], end = rowptr[n + 1];
    float erv = er[n * 8 + hd];

    float acc[8] = {0.f,0.f,0.f,0.f,0.f,0.f,0.f,0.f};
    float expsum = 0.f;

    auto edge = [&](int p) {
        int s = csr_src[p];
        float x = el[s * 8 + hd] + erv;
        x = x > 0.f ? x : NEG * x;
        float w = __expf(x);
        expsum += w;
        uint4 hv = *(const uint4*)(h + (size_t)s * 128 + c16 * 8);
        acc[0] += w * bflo(hv.x); acc[1] += w * bfhi(hv.x);
        acc[2] += w * bflo(hv.y); acc[3] += w * bfhi(hv.y);
        acc[4] += w * bflo(hv.z); acc[5] += w * bfhi(hv.z);
        acc[6] += w * bflo(hv.w); acc[7] += w * bfhi(hv.w);
    };

    int p = begin + q;
    for (; p + 4 < end; p += 8) { edge(p); edge(p + 4); }
    if (p < end) edge(p);

    #pragma unroll
    for (int k = 0; k < 8; ++k) {
        acc[k] += __shfl_xor(acc[k], 32);
        acc[k] += __shfl_xor(acc[k], 16);
    }
    expsum += __shfl_xor(expsum, 32);
    expsum += __shfl_xor(expsum, 16);

    if (q == 0) {
        float inv = expsum > 0.f ? 1.f / expsum : 0.f;
        uint4 hn = *(const uint4*)(h + (size_t)n * 128 + c16 * 8);
        const float4* bp = (const float4*)(bias + c16 * 8);
        float4 b0 = bp[0], b1 = bp[1];
        float4 o0, o1;
        o0.x = acc[0]*inv + bflo(hn.x) + b0.x;
        o0.y = acc[1]*inv + bfhi(hn.x) + b0.y;
        o0.z = acc[2]*inv + bflo(hn.y) + b0.z;
        o0.w = acc[3]*inv + bfhi(hn.y) + b0.w;
        o1.x = acc[4]*inv + bflo(hn.z) + b1.x;
        o1.y = acc[5]*inv + bfhi(hn.z) + b1.y;
        o1.z = acc[6]*inv + bflo(hn.w) + b1.z;
        o1.w = acc[7]*inv + bfhi(hn.w) + b1.w;
        float4* op = (float4*)(out + (size_t)n * 128 + c16 * 8);
        op[0] = o0; op[1] = o1;
    }
}

extern "C" void kernel_launch(void* const* d_in, const int* in_sizes, int n_in,
                              void* d_out, int out_size, void* d_ws, size_t ws_size,
                              hipStream_t stream) {
    const float* feats  = (const float*)d_in[0];
    const float* W      = (const float*)d_in[1];
    const float* attn_l = (const float*)d_in[2];
    const float* attn_r = (const float*)d_in[3];
    const float* bias   = (const float*)d_in[4];
    const int*   src    = (const int*)d_in[5];
    const int*   dst    = (const int*)d_in[6];

    const int N  = in_sizes[0] / 128;
    const int E  = in_sizes[5];
    const int N8 = (N + 7) / 8;
    const int CH = (E + CHUNK - 1) / CHUNK;
    const int GB = (N + 63) / 64;              // gemm blocks
    const int BE = (N * 8 + 255) / 256;        // eler blocks

    float* out = (float*)d_out;
    char*  ws  = (char*)d_ws;
    unsigned short* Wbf = (unsigned short*)ws;         ws += 128 * 128 * 2;
    unsigned short* h = (unsigned short*)ws;           ws += (size_t)N * 128 * 2;
    float* el      = (float*)ws;                       ws += (size_t)N * 8 * 4;
    float* er      = (float*)ws;                       ws += (size_t)N * 8 * 4;
    int*   deg     = (int*)ws;                         ws += (size_t)N * 4;
    int*   rowptr  = (int*)ws;                         ws += (size_t)(N + 1) * 4;
    int*   cursor  = (int*)ws;                         ws += (size_t)N * 4;
    int*   csr_src = (int*)ws;                         ws += (size_t)E * 4;

    hipMemsetAsync(deg, 0, (size_t)N * sizeof(int), stream);

    k_pd        <<<16 + CH * 8, 256, 0, stream>>>(W, Wbf, dst, deg, E, N8);
    k_gemm_scan <<<GB + 1,      256, 0, stream>>>(feats, Wbf, h, deg, rowptr, cursor, N, E, GB);
    k_ef        <<<BE + CH * 8, 256, 0, stream>>>(h, attn_l, attn_r, el, er,
                                                  src, dst, cursor, csr_src, N, E, N8, BE);
    k_agg       <<<(N + 3) / 4, 256, 0, stream>>>(rowptr, csr_src, el, er, h, bias, out, N);
}

// Round 7
// 361.136 us; speedup vs baseline: 1.1995x; 1.1995x over previous
//
#include <hip/hip_runtime.h>

#define NEG 0.2f
#define CHUNK 2048   // edges per CSR-build block (256 thr x 8)

using bf16x8 = __attribute__((ext_vector_type(8))) short;
using f32x4  = __attribute__((ext_vector_type(4))) float;

__device__ __forceinline__ short f2bf(float f) {   // RNE round to bf16 bits
    union { float f; unsigned u; } v; v.f = f;
    unsigned r = v.u + 0x7FFFu + ((v.u >> 16) & 1u);
    return (short)(r >> 16);
}
__device__ __forceinline__ float bflo(unsigned v) {
    union { unsigned u; float f; } x; x.u = v << 16; return x.f;
}
__device__ __forceinline__ float bfhi(unsigned v) {
    union { unsigned u; float f; } x; x.u = v & 0xffff0000u; return x.f;
}

// ---------------------------------------------------------------------------
// k_pd: blocks [0,16) transpose W -> bf16 Wbf[c*128+k] (one-time, 32 KB);
// blocks [16,..) count dst degrees, dst-range partitioned (range r = b&7
// keeps each deg region's atomic lines on ONE XCD under round-robin
// blockIdx->XCD dispatch; the -16 offset preserves the mod-8 phase).
// Both halves are short uniform blocks — no straggler (round-6 lesson).
// ---------------------------------------------------------------------------
__global__ __launch_bounds__(256) void k_pd(const float* __restrict__ W,
                                            unsigned short* __restrict__ Wbf,
                                            const int* __restrict__ dst,
                                            int* __restrict__ deg,
                                            int E, int N8) {
    if (blockIdx.x < 16) {
        int idx = (blockIdx.x * 256 + threadIdx.x) * 4;
        #pragma unroll
        for (int q = 0; q < 4; ++q) {
            int i = idx + q;            // i = k*128 + c
            int k = i >> 7, c = i & 127;
            Wbf[c * 128 + k] = (unsigned short)f2bf(W[i]);
        }
        return;
    }
    int b = blockIdx.x - 16;
    int r = b & 7;
    int c = b >> 3;
    int lo = r * N8, hi = lo + N8;
    int base = c * CHUNK + threadIdx.x;
    #pragma unroll
    for (int q = 0; q < 8; ++q) {
        int e = base + q * 256;
        if (e < E) {
            int d = dst[e];
            if (d >= lo && d < hi) atomicAdd(&deg[d], 1);
        }
    }
}

// ---------------------------------------------------------------------------
// k_gemm: h(bf16) = bf16(feats) @ W via mfma_f32_16x16x32_bf16.
// Wbf (already bf16, transposed) staged into padded LDS with 8 uint4
// copies/thread (vs 64 scalar f2bf+ds_write_b16 in the round-4 version).
// Row stride 136 shorts: 136 = 17*8 keeps b128 alignment, breaks the
// power-of-2 bank stride for the MFMA fragment reads.
// ---------------------------------------------------------------------------
__global__ __launch_bounds__(256) void k_gemm(const float* __restrict__ feats,
                                              const unsigned short* __restrict__ Wbf,
                                              unsigned short* __restrict__ h,
                                              int N) {
    __shared__ short Wt[128 * 136];   // 34816 B
    const int t = threadIdx.x;
    const int n0 = blockIdx.x * 64;

    // stage: 2048 uint4 (32 KB), 8 per thread
    {
        const uint4* Ws = (const uint4*)Wbf;
        #pragma unroll
        for (int i = 0; i < 8; ++i) {
            int g = t * 8 + i;            // uint4 index
            int c = g >> 4, j = g & 15;   // row c, 16 uint4 per row
            *(uint4*)&Wt[c * 136 + j * 8] = Ws[g];
        }
    }
    __syncthreads();

    const int w    = t >> 6;
    const int lane = t & 63;
    const int m    = lane & 15;
    const int quad = lane >> 4;
    const int kq   = quad * 8;

    const int row_a = n0 + w * 16 + m;
    const bool va = (row_a < N);

    f32x4 acc[8];
    #pragma unroll
    for (int ti = 0; ti < 8; ++ti) acc[ti] = (f32x4){0.f, 0.f, 0.f, 0.f};

    #pragma unroll
    for (int kc = 0; kc < 4; ++kc) {
        const float* ap = feats + (size_t)row_a * 128 + kc * 32 + kq;
        float4 a0 = va ? ((const float4*)ap)[0] : make_float4(0.f,0.f,0.f,0.f);
        float4 a1 = va ? ((const float4*)ap)[1] : make_float4(0.f,0.f,0.f,0.f);
        bf16x8 af;
        af[0] = f2bf(a0.x); af[1] = f2bf(a0.y); af[2] = f2bf(a0.z); af[3] = f2bf(a0.w);
        af[4] = f2bf(a1.x); af[5] = f2bf(a1.y); af[6] = f2bf(a1.z); af[7] = f2bf(a1.w);
        #pragma unroll
        for (int ti = 0; ti < 8; ++ti) {
            bf16x8 bf = *(const bf16x8*)&Wt[(ti * 16 + m) * 136 + kc * 32 + kq];
            acc[ti] = __builtin_amdgcn_mfma_f32_16x16x32_bf16(af, bf, acc[ti], 0, 0, 0);
        }
    }

    // C layout: col = ti*16 + m, row = row_d + r
    const int row_d = n0 + w * 16 + quad * 4;
    #pragma unroll
    for (int ti = 0; ti < 8; ++ti) {
        int col = ti * 16 + m;
        #pragma unroll
        for (int r = 0; r < 4; ++r) {
            int row = row_d + r;
            if (row < N) h[(size_t)row * 128 + col] = (unsigned short)f2bf(acc[ti][r]);
        }
    }
}

// ---------------------------------------------------------------------------
// k_eler: el/er per (node, head) from bf16 h.
// ---------------------------------------------------------------------------
__global__ __launch_bounds__(256) void k_eler(const unsigned short* __restrict__ h,
                                              const float* __restrict__ attn_l,
                                              const float* __restrict__ attn_r,
                                              float* __restrict__ el,
                                              float* __restrict__ er,
                                              int N) {
    int t = blockIdx.x * 256 + threadIdx.x;   // t = n*8 + head
    int n = t >> 3, hd = t & 7;
    if (n >= N) return;
    const uint4* hp = (const uint4*)(h + (size_t)n * 128 + hd * 16);
    uint4 u0 = hp[0], u1 = hp[1];
    const float4* al = (const float4*)(attn_l + hd * 16);
    const float4* ar = (const float4*)(attn_r + hd * 16);
    float hv[16];
    hv[0]=bflo(u0.x); hv[1]=bfhi(u0.x); hv[2]=bflo(u0.y); hv[3]=bfhi(u0.y);
    hv[4]=bflo(u0.z); hv[5]=bfhi(u0.z); hv[6]=bflo(u0.w); hv[7]=bfhi(u0.w);
    hv[8]=bflo(u1.x); hv[9]=bfhi(u1.x); hv[10]=bflo(u1.y); hv[11]=bfhi(u1.y);
    hv[12]=bflo(u1.z); hv[13]=bfhi(u1.z); hv[14]=bflo(u1.w); hv[15]=bfhi(u1.w);
    float sl = 0.f, sr = 0.f;
    #pragma unroll
    for (int q = 0; q < 4; ++q) {
        float4 a = al[q], b = ar[q];
        sl += hv[4*q]*a.x + hv[4*q+1]*a.y + hv[4*q+2]*a.z + hv[4*q+3]*a.w;
        sr += hv[4*q]*b.x + hv[4*q+1]*b.y + hv[4*q+2]*b.z + hv[4*q+3]*b.w;
    }
    el[t] = sl;
    er[t] = sr;
}

// ---------------------------------------------------------------------------
// Scan: scan1 (per-1024 block) -> scan2 (parallel, 1 block) -> scan3 (apply).
// ---------------------------------------------------------------------------
__global__ __launch_bounds__(256) void k_scan1(const int* __restrict__ deg,
                                               int* __restrict__ rowptr,
                                               int* __restrict__ partial, int N) {
    __shared__ int sd[256];
    int b = blockIdx.x, t = threadIdx.x;
    int base = b * 1024 + t * 4;
    int v0 = 0, v1 = 0, v2 = 0, v3 = 0;
    if (base + 3 < N) {
        int4 d4 = *(const int4*)(deg + base);
        v0 = d4.x; v1 = d4.y; v2 = d4.z; v3 = d4.w;
    } else {
        if (base + 0 < N) v0 = deg[base];
        if (base + 1 < N) v1 = deg[base + 1];
        if (base + 2 < N) v2 = deg[base + 2];
    }
    int tsum = v0 + v1 + v2 + v3;
    sd[t] = tsum;
    __syncthreads();
    for (int off = 1; off < 256; off <<= 1) {
        int x = (t >= off) ? sd[t - off] : 0;
        __syncthreads();
        sd[t] += x;
        __syncthreads();
    }
    int ex = sd[t] - tsum;
    if (base     < N) rowptr[base]     = ex;
    if (base + 1 < N) rowptr[base + 1] = ex + v0;
    if (base + 2 < N) rowptr[base + 2] = ex + v0 + v1;
    if (base + 3 < N) rowptr[base + 3] = ex + v0 + v1 + v2;
    if (t == 255) partial[b] = sd[255];
}

__global__ __launch_bounds__(256) void k_scan2(const int* __restrict__ partial,
                                               int* __restrict__ partial_ex, int B) {
    __shared__ int sd[256];
    int t = threadIdx.x;
    int v = (t < B) ? partial[t] : 0;
    sd[t] = v;
    __syncthreads();
    for (int off = 1; off < 256; off <<= 1) {
        int x = (t >= off) ? sd[t - off] : 0;
        __syncthreads();
        sd[t] += x;
        __syncthreads();
    }
    if (t < B) partial_ex[t] = sd[t] - v;
}

__global__ __launch_bounds__(256) void k_scan3(int* __restrict__ rowptr,
                                               int* __restrict__ cursor,
                                               const int* __restrict__ partial_ex,
                                               int N, int E) {
    int b = blockIdx.x, t = threadIdx.x;
    int add = partial_ex[b];
    int base = b * 1024 + t * 4;
    #pragma unroll
    for (int q = 0; q < 4; ++q) {
        int i = base + q;
        if (i < N) { int v = rowptr[i] + add; rowptr[i] = v; cursor[i] = v; }
    }
    if (b == 0 && t == 0) rowptr[N] = E;
}

// ---------------------------------------------------------------------------
// k_fill: CSR fill, dst-range partitioned (same XCD-locality trick).
// ---------------------------------------------------------------------------
__global__ __launch_bounds__(256) void k_fill(const int* __restrict__ src,
                                              const int* __restrict__ dst,
                                              int* __restrict__ cursor,
                                              int* __restrict__ csr_src,
                                              int E, int N8) {
    int r = blockIdx.x & 7;
    int c = blockIdx.x >> 3;
    int lo = r * N8, hi = lo + N8;
    int base = c * CHUNK + threadIdx.x;
    #pragma unroll
    for (int q = 0; q < 8; ++q) {
        int e = base + q * 256;
        if (e < E) {
            int d = dst[e];
            if (d >= lo && d < hi) {
                int p = atomicAdd(&cursor[d], 1);
                csr_src[p] = src[e];
            }
        }
    }
}

// ---------------------------------------------------------------------------
// k_agg: gather aggregation, one wave per node; quarter q handles edges
// begin+q, +4, ... with 2-edge unroll (8 edges in flight per wave).
// ---------------------------------------------------------------------------
__global__ __launch_bounds__(256) void k_agg(const int* __restrict__ rowptr,
                                             const int* __restrict__ csr_src,
                                             const float* __restrict__ el,
                                             const float* __restrict__ er,
                                             const unsigned short* __restrict__ h,
                                             const float* __restrict__ bias,
                                             float* __restrict__ out, int N) {
    int t = threadIdx.x;
    int n = blockIdx.x * 4 + (t >> 6);
    if (n >= N) return;
    int lane = t & 63;
    int q    = lane >> 4;      // edge slot 0..3
    int c16  = lane & 15;      // col group: cols 8*c16..8*c16+7
    int hd   = c16 >> 1;
    int begin = rowptr[n], end = rowptr[n + 1];
    float erv = er[n * 8 + hd];

    float acc[8] = {0.f,0.f,0.f,0.f,0.f,0.f,0.f,0.f};
    float expsum = 0.f;

    auto edge = [&](int p) {
        int s = csr_src[p];
        float x = el[s * 8 + hd] + erv;
        x = x > 0.f ? x : NEG * x;
        float w = __expf(x);
        expsum += w;
        uint4 hv = *(const uint4*)(h + (size_t)s * 128 + c16 * 8);
        acc[0] += w * bflo(hv.x); acc[1] += w * bfhi(hv.x);
        acc[2] += w * bflo(hv.y); acc[3] += w * bfhi(hv.y);
        acc[4] += w * bflo(hv.z); acc[5] += w * bfhi(hv.z);
        acc[6] += w * bflo(hv.w); acc[7] += w * bfhi(hv.w);
    };

    int p = begin + q;
    for (; p + 4 < end; p += 8) { edge(p); edge(p + 4); }
    if (p < end) edge(p);

    #pragma unroll
    for (int k = 0; k < 8; ++k) {
        acc[k] += __shfl_xor(acc[k], 32);
        acc[k] += __shfl_xor(acc[k], 16);
    }
    expsum += __shfl_xor(expsum, 32);
    expsum += __shfl_xor(expsum, 16);

    if (q == 0) {
        float inv = expsum > 0.f ? 1.f / expsum : 0.f;
        uint4 hn = *(const uint4*)(h + (size_t)n * 128 + c16 * 8);
        const float4* bp = (const float4*)(bias + c16 * 8);
        float4 b0 = bp[0], b1 = bp[1];
        float4 o0, o1;
        o0.x = acc[0]*inv + bflo(hn.x) + b0.x;
        o0.y = acc[1]*inv + bfhi(hn.x) + b0.y;
        o0.z = acc[2]*inv + bflo(hn.y) + b0.z;
        o0.w = acc[3]*inv + bfhi(hn.y) + b0.w;
        o1.x = acc[4]*inv + bflo(hn.z) + b1.x;
        o1.y = acc[5]*inv + bfhi(hn.z) + b1.y;
        o1.z = acc[6]*inv + bflo(hn.w) + b1.z;
        o1.w = acc[7]*inv + bfhi(hn.w) + b1.w;
        float4* op = (float4*)(out + (size_t)n * 128 + c16 * 8);
        op[0] = o0; op[1] = o1;
    }
}

extern "C" void kernel_launch(void* const* d_in, const int* in_sizes, int n_in,
                              void* d_out, int out_size, void* d_ws, size_t ws_size,
                              hipStream_t stream) {
    const float* feats  = (const float*)d_in[0];
    const float* W      = (const float*)d_in[1];
    const float* attn_l = (const float*)d_in[2];
    const float* attn_r = (const float*)d_in[3];
    const float* bias   = (const float*)d_in[4];
    const int*   src    = (const int*)d_in[5];
    const int*   dst    = (const int*)d_in[6];

    const int N  = in_sizes[0] / 128;
    const int E  = in_sizes[5];
    const int B1 = (N + 1023) / 1024;
    const int N8 = (N + 7) / 8;
    const int CH = (E + CHUNK - 1) / CHUNK;

    float* out = (float*)d_out;
    char*  ws  = (char*)d_ws;
    unsigned short* Wbf = (unsigned short*)ws;         ws += 128 * 128 * 2;
    unsigned short* h = (unsigned short*)ws;           ws += (size_t)N * 128 * 2;
    float* el      = (float*)ws;                       ws += (size_t)N * 8 * 4;
    float* er      = (float*)ws;                       ws += (size_t)N * 8 * 4;
    int*   deg     = (int*)ws;                         ws += (size_t)N * 4;
    int*   rowptr  = (int*)ws;                         ws += (size_t)(N + 1) * 4;
    int*   cursor  = (int*)ws;                         ws += (size_t)N * 4;
    int*   partial = (int*)ws;                         ws += 256 * 4;
    int*   partial_ex = (int*)ws;                      ws += 256 * 4;
    int*   csr_src = (int*)ws;                         ws += (size_t)E * 4;

    hipMemsetAsync(deg, 0, (size_t)N * sizeof(int), stream);

    k_pd   <<<16 + CH * 8,          256, 0, stream>>>(W, Wbf, dst, deg, E, N8);
    k_gemm <<<(N + 63) / 64,        256, 0, stream>>>(feats, Wbf, h, N);
    k_eler <<<(N * 8 + 255) / 256,  256, 0, stream>>>(h, attn_l, attn_r, el, er, N);
    k_scan1<<<B1,                   256, 0, stream>>>(deg, rowptr, partial, N);
    k_scan2<<<1,                    256, 0, stream>>>(partial, partial_ex, B1);
    k_scan3<<<B1,                   256, 0, stream>>>(rowptr, cursor, partial_ex, N, E);
    k_fill <<<CH * 8,               256, 0, stream>>>(src, dst, cursor, csr_src, E, N8);
    k_agg  <<<(N + 3) / 4,          256, 0, stream>>>(rowptr, csr_src, el, er, h, bias, out, N);
}

// Round 8
// 353.723 us; speedup vs baseline: 1.2246x; 1.0210x over previous
//
#include <hip/hip_runtime.h>

#define NEG 0.2f
#define CHUNK 2048   // edges per CSR-build block (256 thr x 8)

using bf16x8 = __attribute__((ext_vector_type(8))) short;
using f32x4  = __attribute__((ext_vector_type(4))) float;

__device__ __forceinline__ short f2bf(float f) {   // RNE round to bf16 bits
    union { float f; unsigned u; } v; v.f = f;
    unsigned r = v.u + 0x7FFFu + ((v.u >> 16) & 1u);
    return (short)(r >> 16);
}
__device__ __forceinline__ float bflo(unsigned v) {
    union { unsigned u; float f; } x; x.u = v << 16; return x.f;
}
__device__ __forceinline__ float bfhi(unsigned v) {
    union { unsigned u; float f; } x; x.u = v & 0xffff0000u; return x.f;
}

// ---------------------------------------------------------------------------
// k_pd: blocks [0,16) transpose W -> bf16 Wbf[c*128+k]; blocks [16,..) count
// dst degrees, dst-range partitioned (r = b&7 keeps each deg region's atomic
// lines on ONE XCD under round-robin blockIdx->XCD dispatch).
// ---------------------------------------------------------------------------
__global__ __launch_bounds__(256) void k_pd(const float* __restrict__ W,
                                            unsigned short* __restrict__ Wbf,
                                            const int* __restrict__ dst,
                                            int* __restrict__ deg,
                                            int E, int N8) {
    if (blockIdx.x < 16) {
        int idx = (blockIdx.x * 256 + threadIdx.x) * 4;
        #pragma unroll
        for (int q = 0; q < 4; ++q) {
            int i = idx + q;            // i = k*128 + c
            int k = i >> 7, c = i & 127;
            Wbf[c * 128 + k] = (unsigned short)f2bf(W[i]);
        }
        return;
    }
    int b = blockIdx.x - 16;
    int r = b & 7;
    int c = b >> 3;
    int lo = r * N8, hi = lo + N8;
    int base = c * CHUNK + threadIdx.x;
    #pragma unroll
    for (int q = 0; q < 8; ++q) {
        int e = base + q * 256;
        if (e < E) {
            int d = dst[e];
            if (d >= lo && d < hi) atomicAdd(&deg[d], 1);
        }
    }
}

// ---------------------------------------------------------------------------
// k_gemm_s1: blocks [0,GB) = bf16 MFMA gemm (Wbf staged to padded LDS with
// 8 uint4 copies/thread); blocks [GB,GB+B1) = scan1 (per-1024 block-local
// exclusive scan of deg -> rowptr, block totals -> partial). Both halves are
// short uniform blocks — safe merge (round-6 straggler lesson).
// ---------------------------------------------------------------------------
__global__ __launch_bounds__(256) void k_gemm_s1(const float* __restrict__ feats,
                                                 const unsigned short* __restrict__ Wbf,
                                                 unsigned short* __restrict__ h,
                                                 const int* __restrict__ deg,
                                                 int* __restrict__ rowptr,
                                                 int* __restrict__ partial,
                                                 int N, int GB) {
    __shared__ short Wt[128 * 136];   // 34816 B (gemm); scan1 reuses low 1KB
    const int t = threadIdx.x;

    if ((int)blockIdx.x >= GB) {
        // ---- scan1 ----
        int* sd = (int*)Wt;
        int b = blockIdx.x - GB;
        int base = b * 1024 + t * 4;
        int v0 = 0, v1 = 0, v2 = 0, v3 = 0;
        if (base + 3 < N) {
            int4 d4 = *(const int4*)(deg + base);
            v0 = d4.x; v1 = d4.y; v2 = d4.z; v3 = d4.w;
        } else {
            if (base + 0 < N) v0 = deg[base];
            if (base + 1 < N) v1 = deg[base + 1];
            if (base + 2 < N) v2 = deg[base + 2];
        }
        int tsum = v0 + v1 + v2 + v3;
        sd[t] = tsum;
        __syncthreads();
        for (int off = 1; off < 256; off <<= 1) {
            int x = (t >= off) ? sd[t - off] : 0;
            __syncthreads();
            sd[t] += x;
            __syncthreads();
        }
        int ex = sd[t] - tsum;
        if (base     < N) rowptr[base]     = ex;
        if (base + 1 < N) rowptr[base + 1] = ex + v0;
        if (base + 2 < N) rowptr[base + 2] = ex + v0 + v1;
        if (base + 3 < N) rowptr[base + 3] = ex + v0 + v1 + v2;
        if (t == 255) partial[b] = sd[255];
        return;
    }

    // ---- gemm ----
    const int n0 = blockIdx.x * 64;
    {
        const uint4* Ws = (const uint4*)Wbf;
        #pragma unroll
        for (int i = 0; i < 8; ++i) {
            int g = t * 8 + i;            // uint4 index
            int c = g >> 4, j = g & 15;   // row c, 16 uint4 per row
            *(uint4*)&Wt[c * 136 + j * 8] = Ws[g];
        }
    }
    __syncthreads();

    const int w    = t >> 6;
    const int lane = t & 63;
    const int m    = lane & 15;
    const int quad = lane >> 4;
    const int kq   = quad * 8;

    const int row_a = n0 + w * 16 + m;
    const bool va = (row_a < N);

    f32x4 acc[8];
    #pragma unroll
    for (int ti = 0; ti < 8; ++ti) acc[ti] = (f32x4){0.f, 0.f, 0.f, 0.f};

    #pragma unroll
    for (int kc = 0; kc < 4; ++kc) {
        const float* ap = feats + (size_t)row_a * 128 + kc * 32 + kq;
        float4 a0 = va ? ((const float4*)ap)[0] : make_float4(0.f,0.f,0.f,0.f);
        float4 a1 = va ? ((const float4*)ap)[1] : make_float4(0.f,0.f,0.f,0.f);
        bf16x8 af;
        af[0] = f2bf(a0.x); af[1] = f2bf(a0.y); af[2] = f2bf(a0.z); af[3] = f2bf(a0.w);
        af[4] = f2bf(a1.x); af[5] = f2bf(a1.y); af[6] = f2bf(a1.z); af[7] = f2bf(a1.w);
        #pragma unroll
        for (int ti = 0; ti < 8; ++ti) {
            bf16x8 bf = *(const bf16x8*)&Wt[(ti * 16 + m) * 136 + kc * 32 + kq];
            acc[ti] = __builtin_amdgcn_mfma_f32_16x16x32_bf16(af, bf, acc[ti], 0, 0, 0);
        }
    }

    // C layout: col = ti*16 + m, row = row_d + r
    const int row_d = n0 + w * 16 + quad * 4;
    #pragma unroll
    for (int ti = 0; ti < 8; ++ti) {
        int col = ti * 16 + m;
        #pragma unroll
        for (int r = 0; r < 4; ++r) {
            int row = row_d + r;
            if (row < N) h[(size_t)row * 128 + col] = (unsigned short)f2bf(acc[ti][r]);
        }
    }
}

// ---------------------------------------------------------------------------
// k_eler_s23: blocks [0,BE) = el/er per (node,head); blocks [BE,BE+B1) =
// fused scan2+scan3: each block re-scans the B1 (<=256) partials in LDS
// (L2-hot, ~1 us) and applies its offset to rowptr/cursor — no separate
// scan2 dispatch, no straggler.
// ---------------------------------------------------------------------------
__global__ __launch_bounds__(256) void k_eler_s23(const unsigned short* __restrict__ h,
                                                  const float* __restrict__ attn_l,
                                                  const float* __restrict__ attn_r,
                                                  float* __restrict__ el,
                                                  float* __restrict__ er,
                                                  const int* __restrict__ partial,
                                                  int* __restrict__ rowptr,
                                                  int* __restrict__ cursor,
                                                  int N, int E, int BE, int B1) {
    if ((int)blockIdx.x >= BE) {
        __shared__ int sd[256];
        int t = threadIdx.x;
        int b = blockIdx.x - BE;
        int v = (t < B1) ? partial[t] : 0;
        sd[t] = v;
        __syncthreads();
        for (int off = 1; off < 256; off <<= 1) {
            int x = (t >= off) ? sd[t - off] : 0;
            __syncthreads();
            sd[t] += x;
            __syncthreads();
        }
        int incl = sd[t];
        __syncthreads();
        sd[t] = incl - v;            // exclusive
        __syncthreads();
        int add = sd[b];
        int base = b * 1024 + t * 4;
        #pragma unroll
        for (int q = 0; q < 4; ++q) {
            int i = base + q;
            if (i < N) { int vv = rowptr[i] + add; rowptr[i] = vv; cursor[i] = vv; }
        }
        if (b == 0 && t == 0) rowptr[N] = E;
        return;
    }

    int t = blockIdx.x * 256 + threadIdx.x;   // t = n*8 + head
    int n = t >> 3, hd = t & 7;
    if (n >= N) return;
    const uint4* hp = (const uint4*)(h + (size_t)n * 128 + hd * 16);
    uint4 u0 = hp[0], u1 = hp[1];
    const float4* al = (const float4*)(attn_l + hd * 16);
    const float4* ar = (const float4*)(attn_r + hd * 16);
    float hv[16];
    hv[0]=bflo(u0.x); hv[1]=bfhi(u0.x); hv[2]=bflo(u0.y); hv[3]=bfhi(u0.y);
    hv[4]=bflo(u0.z); hv[5]=bfhi(u0.z); hv[6]=bflo(u0.w); hv[7]=bfhi(u0.w);
    hv[8]=bflo(u1.x); hv[9]=bfhi(u1.x); hv[10]=bflo(u1.y); hv[11]=bfhi(u1.y);
    hv[12]=bflo(u1.z); hv[13]=bfhi(u1.z); hv[14]=bflo(u1.w); hv[15]=bfhi(u1.w);
    float sl = 0.f, sr = 0.f;
    #pragma unroll
    for (int q = 0; q < 4; ++q) {
        float4 a = al[q], b = ar[q];
        sl += hv[4*q]*a.x + hv[4*q+1]*a.y + hv[4*q+2]*a.z + hv[4*q+3]*a.w;
        sr += hv[4*q]*b.x + hv[4*q+1]*b.y + hv[4*q+2]*b.z + hv[4*q+3]*b.w;
    }
    el[t] = sl;
    er[t] = sr;
}

// ---------------------------------------------------------------------------
// k_fill: CSR fill, dst-range partitioned (XCD-locality trick).
// ---------------------------------------------------------------------------
__global__ __launch_bounds__(256) void k_fill(const int* __restrict__ src,
                                              const int* __restrict__ dst,
                                              int* __restrict__ cursor,
                                              int* __restrict__ csr_src,
                                              int E, int N8) {
    int r = blockIdx.x & 7;
    int c = blockIdx.x >> 3;
    int lo = r * N8, hi = lo + N8;
    int base = c * CHUNK + threadIdx.x;
    #pragma unroll
    for (int q = 0; q < 8; ++q) {
        int e = base + q * 256;
        if (e < E) {
            int d = dst[e];
            if (d >= lo && d < hi) {
                int p = atomicAdd(&cursor[d], 1);
                csr_src[p] = src[e];
            }
        }
    }
}

// ---------------------------------------------------------------------------
// k_agg: gather aggregation, one wave per node; quarter q handles edges
// begin+q, +4, ... with 4-edge unroll (16 loads in flight per wave — one
// full iteration covers the whole node at mean degree 16).
// ---------------------------------------------------------------------------
__global__ __launch_bounds__(256) void k_agg(const int* __restrict__ rowptr,
                                             const int* __restrict__ csr_src,
                                             const float* __restrict__ el,
                                             const float* __restrict__ er,
                                             const unsigned short* __restrict__ h,
                                             const float* __restrict__ bias,
                                             float* __restrict__ out, int N) {
    int t = threadIdx.x;
    int n = blockIdx.x * 4 + (t >> 6);
    if (n >= N) return;
    int lane = t & 63;
    int q    = lane >> 4;      // edge slot 0..3
    int c16  = lane & 15;      // col group: cols 8*c16..8*c16+7
    int hd   = c16 >> 1;
    int begin = rowptr[n], end = rowptr[n + 1];
    float erv = er[n * 8 + hd];

    float acc[8] = {0.f,0.f,0.f,0.f,0.f,0.f,0.f,0.f};
    float expsum = 0.f;

    auto edge = [&](int p) {
        int s = csr_src[p];
        float x = el[s * 8 + hd] + erv;
        x = x > 0.f ? x : NEG * x;
        float w = __expf(x);
        expsum += w;
        uint4 hv = *(const uint4*)(h + (size_t)s * 128 + c16 * 8);
        acc[0] += w * bflo(hv.x); acc[1] += w * bfhi(hv.x);
        acc[2] += w * bflo(hv.y); acc[3] += w * bfhi(hv.y);
        acc[4] += w * bflo(hv.z); acc[5] += w * bfhi(hv.z);
        acc[6] += w * bflo(hv.w); acc[7] += w * bfhi(hv.w);
    };

    int p = begin + q;
    for (; p + 12 < end; p += 16) { edge(p); edge(p + 4); edge(p + 8); edge(p + 12); }
    for (; p < end; p += 4) edge(p);

    #pragma unroll
    for (int k = 0; k < 8; ++k) {
        acc[k] += __shfl_xor(acc[k], 32);
        acc[k] += __shfl_xor(acc[k], 16);
    }
    expsum += __shfl_xor(expsum, 32);
    expsum += __shfl_xor(expsum, 16);

    if (q == 0) {
        float inv = expsum > 0.f ? 1.f / expsum : 0.f;
        uint4 hn = *(const uint4*)(h + (size_t)n * 128 + c16 * 8);
        const float4* bp = (const float4*)(bias + c16 * 8);
        float4 b0 = bp[0], b1 = bp[1];
        float4 o0, o1;
        o0.x = acc[0]*inv + bflo(hn.x) + b0.x;
        o0.y = acc[1]*inv + bfhi(hn.x) + b0.y;
        o0.z = acc[2]*inv + bflo(hn.y) + b0.z;
        o0.w = acc[3]*inv + bfhi(hn.y) + b0.w;
        o1.x = acc[4]*inv + bflo(hn.z) + b1.x;
        o1.y = acc[5]*inv + bfhi(hn.z) + b1.y;
        o1.z = acc[6]*inv + bflo(hn.w) + b1.z;
        o1.w = acc[7]*inv + bfhi(hn.w) + b1.w;
        float4* op = (float4*)(out + (size_t)n * 128 + c16 * 8);
        op[0] = o0; op[1] = o1;
    }
}

extern "C" void kernel_launch(void* const* d_in, const int* in_sizes, int n_in,
                              void* d_out, int out_size, void* d_ws, size_t ws_size,
                              hipStream_t stream) {
    const float* feats  = (const float*)d_in[0];
    const float* W      = (const float*)d_in[1];
    const float* attn_l = (const float*)d_in[2];
    const float* attn_r = (const float*)d_in[3];
    const float* bias   = (const float*)d_in[4];
    const int*   src    = (const int*)d_in[5];
    const int*   dst    = (const int*)d_in[6];

    const int N  = in_sizes[0] / 128;
    const int E  = in_sizes[5];
    const int B1 = (N + 1023) / 1024;          // scan blocks (98)
    const int N8 = (N + 7) / 8;
    const int CH = (E + CHUNK - 1) / CHUNK;
    const int GB = (N + 63) / 64;              // gemm blocks
    const int BE = (N * 8 + 255) / 256;        // eler blocks

    float* out = (float*)d_out;
    char*  ws  = (char*)d_ws;
    unsigned short* Wbf = (unsigned short*)ws;         ws += 128 * 128 * 2;
    unsigned short* h = (unsigned short*)ws;           ws += (size_t)N * 128 * 2;
    float* el      = (float*)ws;                       ws += (size_t)N * 8 * 4;
    float* er      = (float*)ws;                       ws += (size_t)N * 8 * 4;
    int*   deg     = (int*)ws;                         ws += (size_t)N * 4;
    int*   rowptr  = (int*)ws;                         ws += (size_t)(N + 1) * 4;
    int*   cursor  = (int*)ws;                         ws += (size_t)N * 4;
    int*   partial = (int*)ws;                         ws += 256 * 4;
    int*   csr_src = (int*)ws;                         ws += (size_t)E * 4;

    hipMemsetAsync(deg, 0, (size_t)N * sizeof(int), stream);

    k_pd      <<<16 + CH * 8, 256, 0, stream>>>(W, Wbf, dst, deg, E, N8);
    k_gemm_s1 <<<GB + B1,     256, 0, stream>>>(feats, Wbf, h, deg, rowptr, partial, N, GB);
    k_eler_s23<<<BE + B1,     256, 0, stream>>>(h, attn_l, attn_r, el, er,
                                                partial, rowptr, cursor, N, E, BE, B1);
    k_fill    <<<CH * 8,      256, 0, stream>>>(src, dst, cursor, csr_src, E, N8);
    k_agg     <<<(N + 3) / 4, 256, 0, stream>>>(rowptr, csr_src, el, er, h, bias, out, N);
}

// Round 9
// 335.350 us; speedup vs baseline: 1.2917x; 1.0548x over previous
//
#include <hip/hip_runtime.h>

#define NEG 0.2f
#define CHUNK 2048   // edges per CSR-build block (256 thr x 8)

using bf16x8 = __attribute__((ext_vector_type(8))) short;
using f32x4  = __attribute__((ext_vector_type(4))) float;
using f32x2  = __attribute__((ext_vector_type(2))) float;

__device__ __forceinline__ short f2bf(float f) {   // RNE round to bf16 bits
    union { float f; unsigned u; } v; v.f = f;
    unsigned r = v.u + 0x7FFFu + ((v.u >> 16) & 1u);
    return (short)(r >> 16);
}
__device__ __forceinline__ float bflo(unsigned v) {
    union { unsigned u; float f; } x; x.u = v << 16; return x.f;
}
__device__ __forceinline__ float bfhi(unsigned v) {
    union { unsigned u; float f; } x; x.u = v & 0xffff0000u; return x.f;
}

// ---------------------------------------------------------------------------
// k_pd: blocks [0,16) transpose W -> bf16 Wbf[c*128+k]; blocks [16,..) count
// dst degrees, dst-range partitioned (r = b&7 keeps each deg region's atomic
// lines on ONE XCD under round-robin blockIdx->XCD dispatch).
// ---------------------------------------------------------------------------
__global__ __launch_bounds__(256) void k_pd(const float* __restrict__ W,
                                            unsigned short* __restrict__ Wbf,
                                            const int* __restrict__ dst,
                                            int* __restrict__ deg,
                                            int E, int N8) {
    if (blockIdx.x < 16) {
        int idx = (blockIdx.x * 256 + threadIdx.x) * 4;
        #pragma unroll
        for (int q = 0; q < 4; ++q) {
            int i = idx + q;            // i = k*128 + c
            int k = i >> 7, c = i & 127;
            Wbf[c * 128 + k] = (unsigned short)f2bf(W[i]);
        }
        return;
    }
    int b = blockIdx.x - 16;
    int r = b & 7;
    int c = b >> 3;
    int lo = r * N8, hi = lo + N8;
    int base = c * CHUNK + threadIdx.x;
    #pragma unroll
    for (int q = 0; q < 8; ++q) {
        int e = base + q * 256;
        if (e < E) {
            int d = dst[e];
            if (d >= lo && d < hi) atomicAdd(&deg[d], 1);
        }
    }
}

// ---------------------------------------------------------------------------
// k_gemm_s1: blocks [0,GB) = bf16 MFMA gemm (Wbf staged to padded LDS with
// 8 uint4 copies/thread); blocks [GB,GB+B1) = scan1 (per-1024 block-local
// exclusive scan of deg -> rowptr, block totals -> partial).
// ---------------------------------------------------------------------------
__global__ __launch_bounds__(256) void k_gemm_s1(const float* __restrict__ feats,
                                                 const unsigned short* __restrict__ Wbf,
                                                 unsigned short* __restrict__ h,
                                                 const int* __restrict__ deg,
                                                 int* __restrict__ rowptr,
                                                 int* __restrict__ partial,
                                                 int N, int GB) {
    __shared__ short Wt[128 * 136];   // 34816 B (gemm); scan1 reuses low 1KB
    const int t = threadIdx.x;

    if ((int)blockIdx.x >= GB) {
        // ---- scan1 ----
        int* sd = (int*)Wt;
        int b = blockIdx.x - GB;
        int base = b * 1024 + t * 4;
        int v0 = 0, v1 = 0, v2 = 0, v3 = 0;
        if (base + 3 < N) {
            int4 d4 = *(const int4*)(deg + base);
            v0 = d4.x; v1 = d4.y; v2 = d4.z; v3 = d4.w;
        } else {
            if (base + 0 < N) v0 = deg[base];
            if (base + 1 < N) v1 = deg[base + 1];
            if (base + 2 < N) v2 = deg[base + 2];
        }
        int tsum = v0 + v1 + v2 + v3;
        sd[t] = tsum;
        __syncthreads();
        for (int off = 1; off < 256; off <<= 1) {
            int x = (t >= off) ? sd[t - off] : 0;
            __syncthreads();
            sd[t] += x;
            __syncthreads();
        }
        int ex = sd[t] - tsum;
        if (base     < N) rowptr[base]     = ex;
        if (base + 1 < N) rowptr[base + 1] = ex + v0;
        if (base + 2 < N) rowptr[base + 2] = ex + v0 + v1;
        if (base + 3 < N) rowptr[base + 3] = ex + v0 + v1 + v2;
        if (t == 255) partial[b] = sd[255];
        return;
    }

    // ---- gemm ----
    const int n0 = blockIdx.x * 64;
    {
        const uint4* Ws = (const uint4*)Wbf;
        #pragma unroll
        for (int i = 0; i < 8; ++i) {
            int g = t * 8 + i;            // uint4 index
            int c = g >> 4, j = g & 15;   // row c, 16 uint4 per row
            *(uint4*)&Wt[c * 136 + j * 8] = Ws[g];
        }
    }
    __syncthreads();

    const int w    = t >> 6;
    const int lane = t & 63;
    const int m    = lane & 15;
    const int quad = lane >> 4;
    const int kq   = quad * 8;

    const int row_a = n0 + w * 16 + m;
    const bool va = (row_a < N);

    f32x4 acc[8];
    #pragma unroll
    for (int ti = 0; ti < 8; ++ti) acc[ti] = (f32x4){0.f, 0.f, 0.f, 0.f};

    #pragma unroll
    for (int kc = 0; kc < 4; ++kc) {
        const float* ap = feats + (size_t)row_a * 128 + kc * 32 + kq;
        float4 a0 = va ? ((const float4*)ap)[0] : make_float4(0.f,0.f,0.f,0.f);
        float4 a1 = va ? ((const float4*)ap)[1] : make_float4(0.f,0.f,0.f,0.f);
        bf16x8 af;
        af[0] = f2bf(a0.x); af[1] = f2bf(a0.y); af[2] = f2bf(a0.z); af[3] = f2bf(a0.w);
        af[4] = f2bf(a1.x); af[5] = f2bf(a1.y); af[6] = f2bf(a1.z); af[7] = f2bf(a1.w);
        #pragma unroll
        for (int ti = 0; ti < 8; ++ti) {
            bf16x8 bf = *(const bf16x8*)&Wt[(ti * 16 + m) * 136 + kc * 32 + kq];
            acc[ti] = __builtin_amdgcn_mfma_f32_16x16x32_bf16(af, bf, acc[ti], 0, 0, 0);
        }
    }

    // C layout: col = ti*16 + m, row = row_d + r
    const int row_d = n0 + w * 16 + quad * 4;
    #pragma unroll
    for (int ti = 0; ti < 8; ++ti) {
        int col = ti * 16 + m;
        #pragma unroll
        for (int r = 0; r < 4; ++r) {
            int row = row_d + r;
            if (row < N) h[(size_t)row * 128 + col] = (unsigned short)f2bf(acc[ti][r]);
        }
    }
}

// ---------------------------------------------------------------------------
// k_eler_s23: blocks [0,BE) = el/er per (node,head) from bf16 h, AND pack the
// same 16 decoded values to fp8-e4m3 h8 (the gather copy — halves k_agg's
// random-gather bytes; residual/el/er stay bf16/fp32). Blocks [BE,BE+B1) =
// fused scan2+scan3 (re-scan partials in LDS, apply to rowptr/cursor).
// ---------------------------------------------------------------------------
__global__ __launch_bounds__(256) void k_eler_s23(const unsigned short* __restrict__ h,
                                                  const float* __restrict__ attn_l,
                                                  const float* __restrict__ attn_r,
                                                  float* __restrict__ el,
                                                  float* __restrict__ er,
                                                  unsigned char* __restrict__ h8,
                                                  const int* __restrict__ partial,
                                                  int* __restrict__ rowptr,
                                                  int* __restrict__ cursor,
                                                  int N, int E, int BE, int B1) {
    if ((int)blockIdx.x >= BE) {
        __shared__ int sd[256];
        int t = threadIdx.x;
        int b = blockIdx.x - BE;
        int v = (t < B1) ? partial[t] : 0;
        sd[t] = v;
        __syncthreads();
        for (int off = 1; off < 256; off <<= 1) {
            int x = (t >= off) ? sd[t - off] : 0;
            __syncthreads();
            sd[t] += x;
            __syncthreads();
        }
        int incl = sd[t];
        __syncthreads();
        sd[t] = incl - v;            // exclusive
        __syncthreads();
        int add = sd[b];
        int base = b * 1024 + t * 4;
        #pragma unroll
        for (int q = 0; q < 4; ++q) {
            int i = base + q;
            if (i < N) { int vv = rowptr[i] + add; rowptr[i] = vv; cursor[i] = vv; }
        }
        if (b == 0 && t == 0) rowptr[N] = E;
        return;
    }

    int t = blockIdx.x * 256 + threadIdx.x;   // t = n*8 + head
    int n = t >> 3, hd = t & 7;
    if (n >= N) return;
    const uint4* hp = (const uint4*)(h + (size_t)n * 128 + hd * 16);
    uint4 u0 = hp[0], u1 = hp[1];
    const float4* al = (const float4*)(attn_l + hd * 16);
    const float4* ar = (const float4*)(attn_r + hd * 16);
    float hv[16];
    hv[0]=bflo(u0.x); hv[1]=bfhi(u0.x); hv[2]=bflo(u0.y); hv[3]=bfhi(u0.y);
    hv[4]=bflo(u0.z); hv[5]=bfhi(u0.z); hv[6]=bflo(u0.w); hv[7]=bfhi(u0.w);
    hv[8]=bflo(u1.x); hv[9]=bfhi(u1.x); hv[10]=bflo(u1.y); hv[11]=bfhi(u1.y);
    hv[12]=bflo(u1.z); hv[13]=bfhi(u1.z); hv[14]=bflo(u1.w); hv[15]=bfhi(u1.w);

    // fp8 gather copy: 16 values -> 16 bytes, coalesced uint4 store
    unsigned p0 = 0, p1 = 0, p2 = 0, p3 = 0;
    p0 = __builtin_amdgcn_cvt_pk_fp8_f32(hv[0],  hv[1],  p0, false);
    p0 = __builtin_amdgcn_cvt_pk_fp8_f32(hv[2],  hv[3],  p0, true);
    p1 = __builtin_amdgcn_cvt_pk_fp8_f32(hv[4],  hv[5],  p1, false);
    p1 = __builtin_amdgcn_cvt_pk_fp8_f32(hv[6],  hv[7],  p1, true);
    p2 = __builtin_amdgcn_cvt_pk_fp8_f32(hv[8],  hv[9],  p2, false);
    p2 = __builtin_amdgcn_cvt_pk_fp8_f32(hv[10], hv[11], p2, true);
    p3 = __builtin_amdgcn_cvt_pk_fp8_f32(hv[12], hv[13], p3, false);
    p3 = __builtin_amdgcn_cvt_pk_fp8_f32(hv[14], hv[15], p3, true);
    *(uint4*)(h8 + (size_t)n * 128 + hd * 16) = make_uint4(p0, p1, p2, p3);

    float sl = 0.f, sr = 0.f;
    #pragma unroll
    for (int q = 0; q < 4; ++q) {
        float4 a = al[q], b = ar[q];
        sl += hv[4*q]*a.x + hv[4*q+1]*a.y + hv[4*q+2]*a.z + hv[4*q+3]*a.w;
        sr += hv[4*q]*b.x + hv[4*q+1]*b.y + hv[4*q+2]*b.z + hv[4*q+3]*b.w;
    }
    el[t] = sl;
    er[t] = sr;
}

// ---------------------------------------------------------------------------
// k_fill: CSR fill, dst-range partitioned (XCD-locality trick).
// ---------------------------------------------------------------------------
__global__ __launch_bounds__(256) void k_fill(const int* __restrict__ src,
                                              const int* __restrict__ dst,
                                              int* __restrict__ cursor,
                                              int* __restrict__ csr_src,
                                              int E, int N8) {
    int r = blockIdx.x & 7;
    int c = blockIdx.x >> 3;
    int lo = r * N8, hi = lo + N8;
    int base = c * CHUNK + threadIdx.x;
    #pragma unroll
    for (int q = 0; q < 8; ++q) {
        int e = base + q * 256;
        if (e < E) {
            int d = dst[e];
            if (d >= lo && d < hi) {
                int p = atomicAdd(&cursor[d], 1);
                csr_src[p] = src[e];
            }
        }
    }
}

// ---------------------------------------------------------------------------
// k_agg: gather aggregation, one wave per node; quarter q handles edges
// begin+q, +4, ... with 4-edge unroll. Message gather from fp8 h8 (8 B/lane,
// 128 B/edge — half the bf16 bytes); residual from bf16 h; HW cvt decode.
// ---------------------------------------------------------------------------
__global__ __launch_bounds__(256) void k_agg(const int* __restrict__ rowptr,
                                             const int* __restrict__ csr_src,
                                             const float* __restrict__ el,
                                             const float* __restrict__ er,
                                             const unsigned char* __restrict__ h8,
                                             const unsigned short* __restrict__ h,
                                             const float* __restrict__ bias,
                                             float* __restrict__ out, int N) {
    int t = threadIdx.x;
    int n = blockIdx.x * 4 + (t >> 6);
    if (n >= N) return;
    int lane = t & 63;
    int q    = lane >> 4;      // edge slot 0..3
    int c16  = lane & 15;      // col group: cols 8*c16..8*c16+7
    int hd   = c16 >> 1;
    int begin = rowptr[n], end = rowptr[n + 1];
    float erv = er[n * 8 + hd];

    float acc[8] = {0.f,0.f,0.f,0.f,0.f,0.f,0.f,0.f};
    float expsum = 0.f;

    auto edge = [&](int p) {
        int s = csr_src[p];
        float x = el[s * 8 + hd] + erv;
        x = x > 0.f ? x : NEG * x;
        float w = __expf(x);
        expsum += w;
        uint2 hv = *(const uint2*)(h8 + (size_t)s * 128 + c16 * 8);
        f32x2 d0 = __builtin_amdgcn_cvt_pk_f32_fp8(hv.x, false);
        f32x2 d1 = __builtin_amdgcn_cvt_pk_f32_fp8(hv.x, true);
        f32x2 d2 = __builtin_amdgcn_cvt_pk_f32_fp8(hv.y, false);
        f32x2 d3 = __builtin_amdgcn_cvt_pk_f32_fp8(hv.y, true);
        acc[0] += w * d0[0]; acc[1] += w * d0[1];
        acc[2] += w * d1[0]; acc[3] += w * d1[1];
        acc[4] += w * d2[0]; acc[5] += w * d2[1];
        acc[6] += w * d3[0]; acc[7] += w * d3[1];
    };

    int p = begin + q;
    for (; p + 12 < end; p += 16) { edge(p); edge(p + 4); edge(p + 8); edge(p + 12); }
    for (; p < end; p += 4) edge(p);

    #pragma unroll
    for (int k = 0; k < 8; ++k) {
        acc[k] += __shfl_xor(acc[k], 32);
        acc[k] += __shfl_xor(acc[k], 16);
    }
    expsum += __shfl_xor(expsum, 32);
    expsum += __shfl_xor(expsum, 16);

    if (q == 0) {
        float inv = expsum > 0.f ? 1.f / expsum : 0.f;
        uint4 hn = *(const uint4*)(h + (size_t)n * 128 + c16 * 8);
        const float4* bp = (const float4*)(bias + c16 * 8);
        float4 b0 = bp[0], b1 = bp[1];
        float4 o0, o1;
        o0.x = acc[0]*inv + bflo(hn.x) + b0.x;
        o0.y = acc[1]*inv + bfhi(hn.x) + b0.y;
        o0.z = acc[2]*inv + bflo(hn.y) + b0.z;
        o0.w = acc[3]*inv + bfhi(hn.y) + b0.w;
        o1.x = acc[4]*inv + bflo(hn.z) + b1.x;
        o1.y = acc[5]*inv + bfhi(hn.z) + b1.y;
        o1.z = acc[6]*inv + bflo(hn.w) + b1.z;
        o1.w = acc[7]*inv + bfhi(hn.w) + b1.w;
        float4* op = (float4*)(out + (size_t)n * 128 + c16 * 8);
        op[0] = o0; op[1] = o1;
    }
}

extern "C" void kernel_launch(void* const* d_in, const int* in_sizes, int n_in,
                              void* d_out, int out_size, void* d_ws, size_t ws_size,
                              hipStream_t stream) {
    const float* feats  = (const float*)d_in[0];
    const float* W      = (const float*)d_in[1];
    const float* attn_l = (const float*)d_in[2];
    const float* attn_r = (const float*)d_in[3];
    const float* bias   = (const float*)d_in[4];
    const int*   src    = (const int*)d_in[5];
    const int*   dst    = (const int*)d_in[6];

    const int N  = in_sizes[0] / 128;
    const int E  = in_sizes[5];
    const int B1 = (N + 1023) / 1024;          // scan blocks (98)
    const int N8 = (N + 7) / 8;
    const int CH = (E + CHUNK - 1) / CHUNK;
    const int GB = (N + 63) / 64;              // gemm blocks
    const int BE = (N * 8 + 255) / 256;        // eler blocks

    float* out = (float*)d_out;
    char*  ws  = (char*)d_ws;
    unsigned short* Wbf = (unsigned short*)ws;         ws += 128 * 128 * 2;
    unsigned short* h = (unsigned short*)ws;           ws += (size_t)N * 128 * 2;
    unsigned char* h8 = (unsigned char*)ws;            ws += (size_t)N * 128;
    float* el      = (float*)ws;                       ws += (size_t)N * 8 * 4;
    float* er      = (float*)ws;                       ws += (size_t)N * 8 * 4;
    int*   deg     = (int*)ws;                         ws += (size_t)N * 4;
    int*   rowptr  = (int*)ws;                         ws += (size_t)(N + 1) * 4;
    int*   cursor  = (int*)ws;                         ws += (size_t)N * 4;
    int*   partial = (int*)ws;                         ws += 256 * 4;
    int*   csr_src = (int*)ws;                         ws += (size_t)E * 4;

    hipMemsetAsync(deg, 0, (size_t)N * sizeof(int), stream);

    k_pd      <<<16 + CH * 8, 256, 0, stream>>>(W, Wbf, dst, deg, E, N8);
    k_gemm_s1 <<<GB + B1,     256, 0, stream>>>(feats, Wbf, h, deg, rowptr, partial, N, GB);
    k_eler_s23<<<BE + B1,     256, 0, stream>>>(h, attn_l, attn_r, el, er, h8,
                                                partial, rowptr, cursor, N, E, BE, B1);
    k_fill    <<<CH * 8,      256, 0, stream>>>(src, dst, cursor, csr_src, E, N8);
    k_agg     <<<(N + 3) / 4, 256, 0, stream>>>(rowptr, csr_src, el, er, h8, h, bias, out, N);
}